// Round 3
// baseline (107.202 us; speedup 1.0000x reference)
//
#include <hip/hip_runtime.h>

// DropStripes: out[b,t,c] = x[b,t,c] * keep[b,c]
// keep[b,c] = !any_s( c in [bgn[b,s], bgn[b,s]+dist[b,s]) )
// dist = floor(u_dist*64), bgn = floor(u_bgn*(512-dist))
//
// x: (64, 2048, 512) fp32. Memory-bound: 537 MB traffic, roofline ~85us @ 6.3 TB/s.
// Round 1: 102us (5.25 TB/s). This round: 4x unrolled independent loads + NT hints.
// (clang ext_vector_type, since __builtin_nontemporal_* rejects HIP_vector_type)

typedef float f32x4 __attribute__((ext_vector_type(4)));

#define UN 4

__global__ void DropStripes_kernel(const f32x4* __restrict__ x,
                                   const float* __restrict__ u_dist,
                                   const float* __restrict__ u_bgn,
                                   f32x4* __restrict__ out,
                                   int n4) {
    constexpr int W4 = 512 / 4;              // 128 float4 per row
    int tid = blockIdx.x * blockDim.x + threadIdx.x;
    int nthreads = gridDim.x * blockDim.x;
    int big_stride = nthreads * UN;

    for (int base = tid; base < n4; base += big_stride) {
        int   ii[UN];
        f32x4 v[UN];
        bool  ok[UN];

        // Issue all loads first: independent global_load_dwordx4 back-to-back.
        #pragma unroll
        for (int u = 0; u < UN; ++u) {
            ii[u] = base + u * nthreads;
            ok[u] = ii[u] < n4;
            if (ok[u]) v[u] = __builtin_nontemporal_load(&x[ii[u]]);
        }

        #pragma unroll
        for (int u = 0; u < UN; ++u) {
            if (!ok[u]) continue;
            int b  = ii[u] >> 18;                // batch (2048*512/4 = 2^18 float4/batch)
            int c0 = (ii[u] & (W4 - 1)) << 2;    // first channel of this float4

            // Stripe params: 512 B arrays, L1-resident.
            float ud0 = u_dist[2 * b];
            float ud1 = u_dist[2 * b + 1];
            float ub0 = u_bgn[2 * b];
            float ub1 = u_bgn[2 * b + 1];

            int dist0 = (int)floorf(ud0 * 64.0f);
            int dist1 = (int)floorf(ud1 * 64.0f);
            int bgn0  = (int)floorf(ub0 * (float)(512 - dist0));
            int bgn1  = (int)floorf(ub1 * (float)(512 - dist1));
            int end0  = bgn0 + dist0;
            int end1  = bgn1 + dist1;

            #pragma unroll
            for (int j = 0; j < 4; ++j) {
                int c = c0 + j;
                bool drop = (c >= bgn0 && c < end0) || (c >= bgn1 && c < end1);
                v[u][j] = drop ? 0.0f : v[u][j];
            }
        }

        #pragma unroll
        for (int u = 0; u < UN; ++u) {
            if (ok[u]) __builtin_nontemporal_store(v[u], &out[ii[u]]);
        }
    }
}

extern "C" void kernel_launch(void* const* d_in, const int* in_sizes, int n_in,
                              void* d_out, int out_size, void* d_ws, size_t ws_size,
                              hipStream_t stream) {
    const float* x      = (const float*)d_in[0];
    const float* u_dist = (const float*)d_in[1];
    const float* u_bgn  = (const float*)d_in[2];
    float* out          = (float*)d_out;

    int n4 = out_size / 4;                   // 16,777,216 float4
    int block = 256;
    int grid = 4096;                         // 1M threads x UN=4 -> 4 exact passes
    DropStripes_kernel<<<grid, block, 0, stream>>>(
        (const f32x4*)x, u_dist, u_bgn, (f32x4*)out, n4);
}

// Round 4
// 100.254 us; speedup vs baseline: 1.0693x; 1.0693x over previous
//
#include <hip/hip_runtime.h>

// DropStripes: out[b,t,c] = x[b,t,c] * keep[b,c]
// keep[b,c] = !any_s( c in [bgn[b,s], bgn[b,s]+dist[b,s]) )
// dist = floor(u_dist*64), bgn = floor(u_bgn*(512-dist))
//
// x: (64, 2048, 512) fp32. Memory-bound: 537 MB traffic, roofline ~85us @ 6.3 TB/s.
// R1: 102us (5.25 TB/s), per-iter param reloads = 5x VMEM issue of a copy.
// R2: NT+predicated unroll, 107us (regressed).
// R3: block-per-batch mapping -> params loaded ONCE (block-uniform, scalarized);
//     per-thread channel is loop-invariant (stride 256 = 0 mod 128) -> mask
//     multipliers hoisted. Inner loop is a pure copy + 4 v_mul_f32.

typedef float f32x4 __attribute__((ext_vector_type(4)));

__global__ void __launch_bounds__(256)
DropStripes_kernel(const f32x4* __restrict__ x,
                   const float* __restrict__ u_dist,
                   const float* __restrict__ u_bgn,
                   f32x4* __restrict__ out) {
    constexpr int W4 = 512 / 4;                 // 128 float4 per row
    constexpr int N4_PER_BATCH = 2048 * 512 / 4; // 2^18
    constexpr int BLOCKS_PER_BATCH = 128;
    constexpr int CHUNK = N4_PER_BATCH / BLOCKS_PER_BATCH; // 2048 float4
    constexpr int ITERS = CHUNK / 256;          // 8

    int b     = blockIdx.x >> 7;                // block-uniform batch index
    int chunk = blockIdx.x & (BLOCKS_PER_BATCH - 1);
    int base  = b * N4_PER_BATCH + chunk * CHUNK + (int)threadIdx.x;

    // Stripe params: loaded once, block-uniform -> scalarized by compiler.
    float ud0 = u_dist[2 * b];
    float ud1 = u_dist[2 * b + 1];
    float ub0 = u_bgn[2 * b];
    float ub1 = u_bgn[2 * b + 1];

    int dist0 = (int)floorf(ud0 * 64.0f);
    int dist1 = (int)floorf(ud1 * 64.0f);
    int bgn0  = (int)floorf(ub0 * (float)(512 - dist0));
    int bgn1  = (int)floorf(ub1 * (float)(512 - dist1));
    int end0  = bgn0 + dist0;
    int end1  = bgn1 + dist1;

    // Channel quad is loop-invariant: stride 256 == 0 mod 128.
    int c0 = (base & (W4 - 1)) << 2;
    float m[4];
    #pragma unroll
    for (int j = 0; j < 4; ++j) {
        int c = c0 + j;
        bool drop = (c >= bgn0 && c < end0) || (c >= bgn1 && c < end1);
        m[j] = drop ? 0.0f : 1.0f;              // multiply matches ref semantics
    }

    #pragma unroll
    for (int it = 0; it < ITERS; ++it) {
        int i = base + it * 256;
        f32x4 v = x[i];
        v[0] *= m[0];
        v[1] *= m[1];
        v[2] *= m[2];
        v[3] *= m[3];
        out[i] = v;
    }
}

extern "C" void kernel_launch(void* const* d_in, const int* in_sizes, int n_in,
                              void* d_out, int out_size, void* d_ws, size_t ws_size,
                              hipStream_t stream) {
    const float* x      = (const float*)d_in[0];
    const float* u_dist = (const float*)d_in[1];
    const float* u_bgn  = (const float*)d_in[2];
    float* out          = (float*)d_out;

    int grid = 64 * 128;                        // batch x chunk, 8192 blocks
    DropStripes_kernel<<<grid, 256, 0, stream>>>(
        (const f32x4*)x, u_dist, u_bgn, (f32x4*)out);
}

// Round 5
// 88.441 us; speedup vs baseline: 1.2121x; 1.1336x over previous
//
#include <hip/hip_runtime.h>

// DropStripes: out[b,t,c] = x[b,t,c] * keep[b,c]
// keep[b,c] = !any_s( c in [bgn[b,s], bgn[b,s]+dist[b,s]) )
// dist = floor(u_dist*64), bgn = floor(u_bgn*(512-dist))
//
// x: (64, 2048, 512) fp32. Memory-bound: 537 MB traffic, copy ceiling 6.29 TB/s -> ~85us.
// R1: 102us grid-stride scalar-mask. R2: NT+predicated unroll+16MB-stride = 107us
//     (confounded regression: DRAM page locality + predication, NOT proven to be NT).
// R3/R4: block-per-batch, params hoisted to SGPR, mask multipliers loop-invariant,
//     contiguous 4KB iter stride = 100.25us (5.36 TB/s, 85% of copy ceiling).
// R5: isolate NT load+store on the R3 structure (no L2/L3 allocate for zero-reuse
//     streams -> kill cache churn). Everything else unchanged.

typedef float f32x4 __attribute__((ext_vector_type(4)));

__global__ void __launch_bounds__(256)
DropStripes_kernel(const f32x4* __restrict__ x,
                   const float* __restrict__ u_dist,
                   const float* __restrict__ u_bgn,
                   f32x4* __restrict__ out) {
    constexpr int W4 = 512 / 4;                 // 128 float4 per row
    constexpr int N4_PER_BATCH = 2048 * 512 / 4; // 2^18
    constexpr int BLOCKS_PER_BATCH = 128;
    constexpr int CHUNK = N4_PER_BATCH / BLOCKS_PER_BATCH; // 2048 float4
    constexpr int ITERS = CHUNK / 256;          // 8

    int b     = blockIdx.x >> 7;                // block-uniform batch index
    int chunk = blockIdx.x & (BLOCKS_PER_BATCH - 1);
    int base  = b * N4_PER_BATCH + chunk * CHUNK + (int)threadIdx.x;

    // Stripe params: loaded once, block-uniform -> scalarized (s_load).
    float ud0 = u_dist[2 * b];
    float ud1 = u_dist[2 * b + 1];
    float ub0 = u_bgn[2 * b];
    float ub1 = u_bgn[2 * b + 1];

    int dist0 = (int)floorf(ud0 * 64.0f);
    int dist1 = (int)floorf(ud1 * 64.0f);
    int bgn0  = (int)floorf(ub0 * (float)(512 - dist0));
    int bgn1  = (int)floorf(ub1 * (float)(512 - dist1));
    int end0  = bgn0 + dist0;
    int end1  = bgn1 + dist1;

    // Channel quad is loop-invariant: stride 256 == 0 mod 128.
    int c0 = (base & (W4 - 1)) << 2;
    float m[4];
    #pragma unroll
    for (int j = 0; j < 4; ++j) {
        int c = c0 + j;
        bool drop = (c >= bgn0 && c < end0) || (c >= bgn1 && c < end1);
        m[j] = drop ? 0.0f : 1.0f;              // multiply matches ref semantics
    }

    #pragma unroll
    for (int it = 0; it < ITERS; ++it) {
        int i = base + it * 256;                // +4KB per iter: DRAM-page friendly
        f32x4 v = __builtin_nontemporal_load(&x[i]);
        v[0] *= m[0];
        v[1] *= m[1];
        v[2] *= m[2];
        v[3] *= m[3];
        __builtin_nontemporal_store(v, &out[i]);
    }
}

extern "C" void kernel_launch(void* const* d_in, const int* in_sizes, int n_in,
                              void* d_out, int out_size, void* d_ws, size_t ws_size,
                              hipStream_t stream) {
    const float* x      = (const float*)d_in[0];
    const float* u_dist = (const float*)d_in[1];
    const float* u_bgn  = (const float*)d_in[2];
    float* out          = (float*)d_out;

    int grid = 64 * 128;                        // batch x chunk, 8192 blocks
    DropStripes_kernel<<<grid, 256, 0, stream>>>(
        (const f32x4*)x, u_dist, u_bgn, (f32x4*)out);
}